// Round 16
// baseline (97.786 us; speedup 1.0000x reference)
//
#include <hip/hip_runtime.h>
#include <math.h>

// MoE router: logits = x @ gate_w  (M=32768, K=2048, N=64 fp32)
// Split-precision MFMA: x,w -> 2 fp16 limbs each; logits = xh*wh + xh*wl + xl*wh.
// Scaling: x*64, w*256 (denormal safety), descale 2^-14 at epilogue.
// R16: A-path coalesced: global_load_lds (pre-swizzled source, R7-proven) into
//      per-wave-private double-buffered LDS; ds_read_b128 fragments; counted
//      vmcnt (no barriers in K-loop). B = register single set. 16 waves/CU.
// outputs (concat flat, read back as float32):
//   [0 .. 2N)   top_k_weights [N,2]
//   [2N .. 4N)  top_k_indices [N,2] (as float values)
//   [4N]        load_balance_loss scalar
#define N_TOKENS 32768
#define HIDDEN   2048
#define NEXP     64
#define BM 32                   // tokens per block
#define NWAVE 4                 // 256 threads; wave wv owns K-quarter wv
#define NBLK (N_TOKENS / BM)    // 1024
#define KSTEP 32
#define NSTEP 16                // K-quarter (512) / KSTEP
#define XSCALE 64.f
#define WSCALE 256.f
#define DESCALE (1.f / 16384.f)
#define NG 64

typedef __attribute__((ext_vector_type(8))) _Float16 half8;
typedef __attribute__((ext_vector_type(4))) float f32x4;

__device__ __forceinline__ void gload16(const void* g, void* l) {
    __builtin_amdgcn_global_load_lds(
        (const __attribute__((address_space(1))) void*)g,
        (__attribute__((address_space(3))) void*)l, 16, 0, 0);
}

// ---- kernel 0: split gate_w into 2 fp16 limb planes, MFMA-fragment-packed ----
// plane order: [(S*4 + nt)*64 + lane]*8 + j  <=>  w[32S + (lane>>4)*8 + j][nt*16 + (lane&15)]
__global__ void wsplit_kernel(const float* __restrict__ gw,
                              _Float16* __restrict__ wh, _Float16* __restrict__ wl) {
    __shared__ float tile[KSTEP * NEXP];
    const int S   = blockIdx.x;
    const int tid = threadIdx.x;
    const float4* g4 = reinterpret_cast<const float4*>(gw + (size_t)S * KSTEP * NEXP);
    float4* t4 = reinterpret_cast<float4*>(tile);
    t4[tid]       = g4[tid];
    t4[tid + 256] = g4[tid + 256];
    __syncthreads();
    const int nt  = tid >> 6;
    const int l   = tid & 63;
    const int col = nt * 16 + (l & 15);
    const int kr  = (l >> 4) * 8;
    half8 vh, vl;
    #pragma unroll
    for (int j = 0; j < 8; ++j) {
        const float w = tile[(kr + j) * NEXP + col] * WSCALE;
        const _Float16 hh = (_Float16)w;
        vh[j] = hh;
        vl[j] = (_Float16)(w - (float)hh);
    }
    const size_t off = ((size_t)(S * 4 + nt) * 64 + l) * 8;
    *reinterpret_cast<half8*>(wh + off) = vh;
    *reinterpret_cast<half8*>(wl + off) = vl;
}

__global__ __launch_bounds__(256, 4)
void router_main(const float* __restrict__ x,
                 const _Float16* __restrict__ whp, const _Float16* __restrict__ wlp,
                 float* __restrict__ out_w, float* __restrict__ out_i,
                 float* __restrict__ wsP, int* __restrict__ wsC)
{
    // arena: A staging [2 buf][4 wv][1024 f] = 8192 f; reused as part[4][32][65] = 8320 f
    __shared__ __align__(16) float arena[8320];
    __shared__ float pred[NWAVE][NEXP];
    __shared__ int   cntl[NEXP];

    const int tid  = threadIdx.x;
    const int lane = tid & 63;
    const int wv   = tid >> 6;         // K-quarter id
    const int m0   = blockIdx.x * BM;
    if (tid < NEXP) cntl[tid] = 0;

    const int Sb   = wv * NSTEP;       // K-step base
    const int wvK  = wv * 512;         // K float base
    const int wvA  = wv * 1024;        // LDS float base (per-wave staging region)

    // A staging decomposition (R7-proven): instr i covers tokens i*8..i*8+7
    const int stok = lane >> 3;        // token within 8-row group
    const int su   = (lane & 7) ^ stok;// swizzled 16B unit (XOR pre-swizzle on source)
    // A fragment read constants (R7-proven)
    const int t7   = lane & 7;
    const int vb   = (lane >> 4) * 2;

    half8 bh[4], bl[4];                // B single register set
    f32x4 acc[2][4];
    const f32x4 zero = {0.f, 0.f, 0.f, 0.f};
    #pragma unroll
    for (int mt = 0; mt < 2; ++mt)
        #pragma unroll
        for (int nt = 0; nt < 4; ++nt) acc[mt][nt] = zero;

    #define STAGEA(s_, buf_) {                                                        \
        const int k0_ = wvK + (s_) * KSTEP;                                           \
        _Pragma("unroll")                                                             \
        for (int i = 0; i < 4; ++i) {                                                 \
            const float* g_ = x + (size_t)(m0 + i * 8 + stok) * HIDDEN + k0_ + su * 4;\
            gload16(g_, arena + (buf_) * 4096 + wvA + i * 256);                       \
        } }
    #define LOADB(s_) {                                                               \
        const int S_ = Sb + (s_);                                                     \
        _Pragma("unroll")                                                             \
        for (int nt = 0; nt < 4; ++nt) {                                              \
            const size_t o_ = ((size_t)(S_ * 4 + nt) * 64 + lane) * 8;                \
            bh[nt] = *reinterpret_cast<const half8*>(whp + o_);                       \
            bl[nt] = *reinterpret_cast<const half8*>(wlp + o_);                       \
        } }
    // one K-step: wait A(s), read frags, (stage A(s+2)), compute, (load B(s+1))
    #define BODY(s_, VMC, DO_STAGE, DO_LOADB) {                                       \
        asm volatile("s_waitcnt vmcnt(" #VMC ")" ::: "memory");                       \
        __builtin_amdgcn_sched_barrier(0);                                            \
        const float* abase_ = arena + ((s_) & 1) * 4096 + wvA;                        \
        f32x4 q_[2][2];                                                               \
        _Pragma("unroll")                                                             \
        for (int mt = 0; mt < 2; ++mt) {                                              \
            const float* xrow_ = abase_ + (mt * 16 + (lane & 15)) * 32;               \
            q_[mt][0] = *reinterpret_cast<const f32x4*>(xrow_ + ((vb ^ t7) << 2));    \
            q_[mt][1] = *reinterpret_cast<const f32x4*>(xrow_ + (((vb + 1) ^ t7) << 2)); \
        }                                                                             \
        asm volatile("s_waitcnt lgkmcnt(0)" ::: "memory");                            \
        __builtin_amdgcn_sched_barrier(0);                                            \
        if (DO_STAGE) STAGEA((s_) + 2, (s_) & 1);                                     \
        half8 ah_[2], al_[2];                                                         \
        _Pragma("unroll")                                                             \
        for (int mt = 0; mt < 2; ++mt)                                                \
            _Pragma("unroll")                                                         \
            for (int h = 0; h < 2; ++h)                                               \
                _Pragma("unroll")                                                     \
                for (int j = 0; j < 4; ++j) {                                         \
                    const float v_ = q_[mt][h][j] * XSCALE;                           \
                    const _Float16 hh_ = (_Float16)v_;                                \
                    ah_[mt][h * 4 + j] = hh_;                                         \
                    al_[mt][h * 4 + j] = (_Float16)(v_ - (float)hh_);                 \
                }                                                                     \
        _Pragma("unroll")                                                             \
        for (int mt = 0; mt < 2; ++mt)                                                \
            _Pragma("unroll")                                                         \
            for (int nt = 0; nt < 4; ++nt) {                                          \
                f32x4 c_ = acc[mt][nt];                                               \
                c_ = __builtin_amdgcn_mfma_f32_16x16x32_f16(ah_[mt], bh[nt], c_, 0, 0, 0); \
                c_ = __builtin_amdgcn_mfma_f32_16x16x32_f16(ah_[mt], bl[nt], c_, 0, 0, 0); \
                c_ = __builtin_amdgcn_mfma_f32_16x16x32_f16(al_[mt], bh[nt], c_, 0, 0, 0); \
                acc[mt][nt] = c_;                                                     \
            }                                                                         \
        if (DO_LOADB) LOADB((s_) + 1);                                                \
    }

    // prologue (issue order matters for the vmcnt counts): A(0), A(1), B(0)
    STAGEA(0, 0); STAGEA(1, 1); LOADB(0);

    // iter 0: issued after A(0) = A(1) 4 + B(0) 8 = 12
    BODY(0, 12, 1, 1);
    // steady state s=1..14: issued after A(s) = B(s-1) 8 + A(s+1) 4 + B(s) 8 = 20
    for (int t = 0; t < 7; ++t) {
        const int s = 1 + t * 2;
        BODY(s, 20, 1, 1);                     // odd s
        BODY(s + 1, 20, (s + 1) < 14, 1);      // even s; stage while s+3<=15
    }
    // tail s=15: issued after A(15) = B(14) 8 + B(15) 8 = 16
    BODY(15, 16, 0, 0);
    #undef STAGEA
    #undef LOADB
    #undef BODY

    // all waves done reading their staging regions before arena is reused as part[]
    __syncthreads();
    {   // part[wv] = arena + wv*2080 : [32 tok][65]
        float* part = arena + wv * (BM * 65);
        #pragma unroll
        for (int mt = 0; mt < 2; ++mt)
            #pragma unroll
            for (int nt = 0; nt < 4; ++nt)
                #pragma unroll
                for (int r = 0; r < 4; ++r)
                    part[(mt * 16 + (lane >> 4) * 4 + r) * 65 + nt * 16 + (lane & 15)] =
                        acc[mt][nt][r] * DESCALE;
    }
    __syncthreads();

    // epilogue: wave wv handles tokens wv*8..+7; lane = expert
    float sumP = 0.f;
    for (int t = 0; t < BM / NWAVE; ++t) {
        const int m = wv * (BM / NWAVE) + t;
        const float l = arena[0 * (BM * 65) + m * 65 + lane]
                      + arena[1 * (BM * 65) + m * 65 + lane]
                      + arena[2 * (BM * 65) + m * 65 + lane]
                      + arena[3 * (BM * 65) + m * 65 + lane];

        // top-1 (max value, lowest index on tie — matches jax.lax.top_k)
        float v = l; int idx = lane;
        #pragma unroll
        for (int off = 32; off >= 1; off >>= 1) {
            float ov = __shfl_xor(v, off);
            int   oi = __shfl_xor(idx, off);
            if (ov > v || (ov == v && oi < idx)) { v = ov; idx = oi; }
        }
        const float v1 = v; const int i1 = idx;
        // top-2
        v = (lane == i1) ? -INFINITY : l;
        idx = lane;
        #pragma unroll
        for (int off = 32; off >= 1; off >>= 1) {
            float ov = __shfl_xor(v, off);
            int   oi = __shfl_xor(idx, off);
            if (ov > v || (ov == v && oi < idx)) { v = ov; idx = oi; }
        }
        const float v2 = v; const int i2 = idx;
        // softmax over the two top logits (stable: v2 - v1 <= 0)
        const float ed  = expf(v2 - v1);
        const float wt1 = 1.f / (1.f + ed);
        const float wt2 = ed / (1.f + ed);
        // full softmax over 64 experts (max is v1)
        const float p = expf(l - v1);
        float Z = p;
        #pragma unroll
        for (int off = 32; off >= 1; off >>= 1) Z += __shfl_xor(Z, off);
        sumP += p / Z;
        if (lane == 0) {
            const size_t o = (size_t)(m0 + m) * 2;
            out_w[o]     = wt1;
            out_w[o + 1] = wt2;
            out_i[o]     = (float)i1;
            out_i[o + 1] = (float)i2;
            atomicAdd(&cntl[i1], 1);
            atomicAdd(&cntl[i2], 1);
        }
    }
    pred[wv][lane] = sumP;
    __syncthreads();
    if (tid < NEXP) {
        float s = 0.f;
        #pragma unroll
        for (int w2 = 0; w2 < NWAVE; ++w2) s += pred[w2][tid];
        wsP[(size_t)blockIdx.x * NEXP + tid] = s;
        wsC[(size_t)blockIdx.x * NEXP + tid] = cntl[tid];
    }
}

// ---- finalize stage 1 ----
__global__ void router_fin1(const float* __restrict__ wsP, const int* __restrict__ wsC,
                            float* __restrict__ Ps1, float* __restrict__ Cs1)
{
    const int g = blockIdx.x;
    const int e = threadIdx.x;
    float P = 0.f, C = 0.f;
    #pragma unroll
    for (int r = 0; r < NBLK / NG; ++r) {
        const size_t row = (size_t)(g * (NBLK / NG) + r) * NEXP + e;
        P += wsP[row];
        C += (float)wsC[row];
    }
    Ps1[(size_t)g * NEXP + e] = P;
    Cs1[(size_t)g * NEXP + e] = C;
}

// ---- finalize stage 2 ----
__global__ void router_fin2(const float* __restrict__ Ps1, const float* __restrict__ Cs1,
                            float* __restrict__ out_loss)
{
    const int e = threadIdx.x;
    float P = 0.f, C = 0.f;
    #pragma unroll
    for (int g = 0; g < NG; ++g) {
        P += Ps1[(size_t)g * NEXP + e];
        C += Cs1[(size_t)g * NEXP + e];
    }
    float val = (C / (float)N_TOKENS) * (P / (float)N_TOKENS);
    #pragma unroll
    for (int off = 32; off >= 1; off >>= 1) val += __shfl_xor(val, off);
    if (e == 0) out_loss[0] = (float)NEXP * val;
}

extern "C" void kernel_launch(void* const* d_in, const int* in_sizes, int n_in,
                              void* d_out, int out_size, void* d_ws, size_t ws_size,
                              hipStream_t stream) {
    const float* x  = (const float*)d_in[0];
    const float* gw = (const float*)d_in[1];
    float* out   = (float*)d_out;
    float* out_w = out;                        // [N,2] weights
    float* out_i = out + (size_t)N_TOKENS * 2; // [N,2] indices (as floats)
    float* loss  = out + (size_t)N_TOKENS * 4; // scalar
    float*    wsP = (float*)d_ws;                                    // 256 KB (1024x64 f32)
    int*      wsC = (int*)((char*)d_ws + 262144);                    // 256 KB
    _Float16* wh  = (_Float16*)((char*)d_ws + 524288);               // 256 KB
    _Float16* wl  = wh + (size_t)HIDDEN * NEXP;                      // 256 KB
    float*    Ps1 = (float*)((char*)d_ws + 1048576);                 // 16 KB
    float*    Cs1 = Ps1 + NG * NEXP;                                 // 16 KB
    hipLaunchKernelGGL(wsplit_kernel, dim3(HIDDEN / KSTEP), dim3(256), 0, stream, gw, wh, wl);
    hipLaunchKernelGGL(router_main, dim3(NBLK), dim3(256), 0, stream,
                       x, wh, wl, out_w, out_i, wsP, wsC);
    hipLaunchKernelGGL(router_fin1, dim3(NG), dim3(64), 0, stream, wsP, wsC, Ps1, Cs1);
    hipLaunchKernelGGL(router_fin2, dim3(1), dim3(64), 0, stream, Ps1, Cs1, loss);
}